// Round 10
// baseline (2255.896 us; speedup 1.0000x reference)
//
#include <hip/hip_runtime.h>

#define T_LEN 2050
#define B_SZ 128
#define NCHUNK 33               // chunks of steps t=1..2049
#define HL2PI 0.91893853320467274178f

// ---------- wave-wide helpers (wave = 64 lanes) ----------
__device__ __forceinline__ float waveMax(float v) {
#pragma unroll
    for (int off = 32; off >= 1; off >>= 1)
        v = fmaxf(v, __shfl_xor(v, off, 64));
    return v;
}
__device__ __forceinline__ float waveSum(float v) {
#pragma unroll
    for (int off = 32; off >= 1; off >>= 1)
        v += __shfl_xor(v, off, 64);
    return v;
}
__device__ __forceinline__ void waveArgmax(float& v, int& idx) {
#pragma unroll
    for (int off = 32; off >= 1; off >>= 1) {
        float ov = __shfl_xor(v, off, 64);
        int   oi = __shfl_xor(idx, off, 64);
        if (ov > v || (ov == v && oi < idx)) { v = ov; idx = oi; }
    }
}
__device__ __forceinline__ void cfence() { asm volatile("" ::: "memory"); }

// DPP full-wave reductions (rounds 5-9 proven)
__device__ __forceinline__ float dppSumAll(float v) {
#define SSTEP(ctrl) { int t_ = __builtin_amdgcn_update_dpp(0, __float_as_int(v), ctrl, 0xf, 0xf, true); \
                      v = v + __int_as_float(t_); }
    SSTEP(0x111) SSTEP(0x112) SSTEP(0x114) SSTEP(0x118) SSTEP(0x142) SSTEP(0x143)
#undef SSTEP
    return __int_as_float(__builtin_amdgcn_readlane(__float_as_int(v), 63));
}
__device__ __forceinline__ float dppMaxAll(float v) {
#define MSTEP(ctrl) { int t_ = __builtin_amdgcn_update_dpp(__float_as_int(v), __float_as_int(v), ctrl, 0xf, 0xf, false); \
                      v = fmaxf(v, __int_as_float(t_)); }
    MSTEP(0x111) MSTEP(0x112) MSTEP(0x114) MSTEP(0x118) MSTEP(0x142) MSTEP(0x143)
#undef MSTEP
    return __int_as_float(__builtin_amdgcn_readlane(__float_as_int(v), 63));
}
__device__ __forceinline__ float rlane(int bits, int lane) {
    return __int_as_float(__builtin_amdgcn_readlane(bits, lane));
}

// ===== prep: log_softmax(log_A) -> lAg[c*64+i] (column-major), log_softmax(log_pi) =====
extern "C" __global__ __launch_bounds__(64, 1)
void hmm_prep(const float* __restrict__ logA_in,
              const float* __restrict__ logpi_in,
              float* __restrict__ lAg,
              float* __restrict__ lpig)
{
    __shared__ float la[64 * 65];
    __shared__ float rowlse[64];
    const int j = threadIdx.x;
#pragma unroll
    for (int k = 0; k < 64; ++k)
        la[k * 65 + j] = logA_in[k * 64 + j];
    cfence();
    {   // exact op order (rounds 1..9 proven)
        float m = -1e30f;
#pragma unroll
        for (int k = 0; k < 64; ++k) m = fmaxf(m, la[j * 65 + k]);
        float s = 0.f;
#pragma unroll
        for (int k = 0; k < 64; ++k) s += expf(la[j * 65 + k] - m);
        rowlse[j] = m + logf(s);
    }
    cfence();
    {
        float v = logpi_in[j];
        float m = waveMax(v);
        float s = waveSum(expf(v - m));
        lpig[j] = v - (m + logf(s));
    }
    float4* o = (float4*)lAg;
#pragma unroll
    for (int k = 0; k < 16; ++k) {
        float4 v;
        v.x = la[(4 * k + 0) * 65 + j] - rowlse[4 * k + 0];
        v.y = la[(4 * k + 1) * 65 + j] - rowlse[4 * k + 1];
        v.z = la[(4 * k + 2) * 65 + j] - rowlse[4 * k + 2];
        v.w = la[(4 * k + 3) * 65 + j] - rowlse[4 * k + 3];
        o[j * 16 + k] = v;
    }
}

// ===== emission precompute (EXACT op order, round-2 proven bit-exact) -> buf[b][t][64] =====
extern "C" __global__ __launch_bounds__(256)
void hmm_emis(const float* __restrict__ x,
              const float* __restrict__ means,
              const float* __restrict__ stds,
              float* __restrict__ buf)
{
    const int wid = blockIdx.x * 4 + (threadIdx.x >> 6);
    const int j = threadIdx.x & 63;
    const int t = wid >> 7;          // wid = t*128 + b
    const int b = wid & 127;

    const float* xt = x + ((size_t)b * T_LEN + t) * 6;
    float x0 = xt[0], x1 = xt[1], x2 = xt[2], x3 = xt[3];

    float mu0 = means[j * 6 + 0], mu1 = means[j * 6 + 1];
    float mu2 = means[j * 6 + 2], mu3 = means[j * 6 + 3];
    float sg0 = fmaxf(stds[j * 6 + 0], 0.f) + 0.1f;
    float sg1 = fmaxf(stds[j * 6 + 1], 0.f) + 0.1f;
    float sg2 = fmaxf(stds[j * 6 + 2], 0.f) + 0.1f;
    float sg3 = fmaxf(stds[j * 6 + 3], 0.f) + 0.1f;
    float ls0 = logf(sg0), ls1 = logf(sg1), ls2 = logf(sg2), ls3 = logf(sg3);

    float z0 = (x0 - mu0) / sg0, z1 = (x1 - mu1) / sg1;
    float z2 = (x2 - mu2) / sg2, z3 = (x3 - mu3) / sg3;
    float e0 = ((-0.5f * z0) * z0 - ls0) - HL2PI;
    float e1 = ((-0.5f * z1) * z1 - ls1) - HL2PI;
    float e2 = ((-0.5f * z2) * z2 - ls2) - HL2PI;
    float e3 = ((-0.5f * z3) * z3 - ls3) - HL2PI;
    float lp = ((e0 + e1) + e2) + e3;

    buf[((size_t)b * T_LEN + t) * 64 + j] = lp;
}

// ===== main: TWO independent chains per wave (fills hazard slots).
// blocks 0..63: forward for b=2p,2p+1 -> out; blocks 64..127: viterbi for 2 batches =====
extern "C" __global__ __launch_bounds__(64, 1)
void hmm_main(const float* __restrict__ x,
              const float* __restrict__ means,
              const float* __restrict__ stds,
              const float* __restrict__ lAg,
              const float* __restrict__ lpig,
              float* __restrict__ out,
              float* __restrict__ buf,
              int* __restrict__ c_last)
{
    __shared__ __align__(16) float xs[2 * 12304];   // 98.4 KB (forward blocks only)

    const int j   = threadIdx.x;
    const int bid = blockIdx.x;
    const bool is_fwd = (bid < 64);
    const int p = is_fwd ? bid : bid - 64;
    const int b0 = 2 * p, b1 = 2 * p + 1;

    float lpi = lpig[j];

    if (is_fwd) {
        // stage both batches' x
        {
            const float4* xg0 = (const float4*)(x + (size_t)b0 * T_LEN * 6);
            const float4* xg1 = (const float4*)(x + (size_t)b1 * T_LEN * 6);
            float4* xs0 = (float4*)xs;
            float4* xs1 = (float4*)(xs + 12304);
            for (int i = j; i < 3075; i += 64) { xs0[i] = xg0[i]; xs1[i] = xg1[i]; }
        }
        float mu0 = means[j * 6 + 0], mu1 = means[j * 6 + 1];
        float mu2 = means[j * 6 + 2], mu3 = means[j * 6 + 3];
        float sg0 = fmaxf(stds[j * 6 + 0], 0.f) + 0.1f;
        float sg1 = fmaxf(stds[j * 6 + 1], 0.f) + 0.1f;
        float sg2 = fmaxf(stds[j * 6 + 2], 0.f) + 0.1f;
        float sg3 = fmaxf(stds[j * 6 + 3], 0.f) + 0.1f;
        float ls0 = logf(sg0), ls1 = logf(sg1), ls2 = logf(sg2), ls3 = logf(sg3);
        float i0 = 1.f / sg0, i1 = 1.f / sg1, i2 = 1.f / sg2, i3 = 1.f / sg3;
        float cst = -(ls0 + ls1 + ls2 + ls3) - 4.f * HL2PI;

        float Ac[64];     // shared by both chains (same A)
        {
            const float4* g = (const float4*)lAg;
#pragma unroll
            for (int k = 0; k < 16; ++k) {
                float4 v = g[j * 16 + k];
                Ac[4 * k + 0] = __expf(v.x); Ac[4 * k + 1] = __expf(v.y);
                Ac[4 * k + 2] = __expf(v.z); Ac[4 * k + 3] = __expf(v.w);
            }
        }
        cfence();   // xs staged (same-wave in-order DS)

        const float* X0 = xs;
        const float* X1 = xs + 12304;

        // t = 0 (both chains; round-9 proven math)
        float u0, u1; double acc0, acc1;
        {
            float a = (cst - 0.5f * (((X0[0]-mu0)*i0)*((X0[0]-mu0)*i0) + ((X0[1]-mu1)*i1)*((X0[1]-mu1)*i1)
                                   + ((X0[2]-mu2)*i2)*((X0[2]-mu2)*i2) + ((X0[3]-mu3)*i3)*((X0[3]-mu3)*i3))) + lpi;
            float m = dppMaxAll(a);
            u0 = __expf(a - m);
            float s = dppSumAll(u0);
            acc0 = (double)(m + __logf(s));
            u0 *= (1.0f / s);
        }
        {
            float a = (cst - 0.5f * (((X1[0]-mu0)*i0)*((X1[0]-mu0)*i0) + ((X1[1]-mu1)*i1)*((X1[1]-mu1)*i1)
                                   + ((X1[2]-mu2)*i2)*((X1[2]-mu2)*i2) + ((X1[3]-mu3)*i3)*((X1[3]-mu3)*i3))) + lpi;
            float m = dppMaxAll(a);
            u1 = __expf(a - m);
            float s = dppSumAll(u1);
            acc1 = (double)(m + __logf(s));
            u1 *= (1.0f / s);
        }

        // pipeline emissions for t = 1
        float mm_c0, e_c0, mm_c1, e_c1;
        {
            float w0 = (X0[6]-mu0)*i0, w1 = (X0[7]-mu1)*i1, w2 = (X0[8]-mu2)*i2, w3 = (X0[9]-mu3)*i3;
            float lp = cst - 0.5f * (w0*w0 + w1*w1 + w2*w2 + w3*w3);
            mm_c0 = dppMaxAll(lp); e_c0 = __expf(lp - mm_c0);
            float v0 = (X1[6]-mu0)*i0, v1 = (X1[7]-mu1)*i1, v2 = (X1[8]-mu2)*i2, v3 = (X1[9]-mu3)*i3;
            float lq = cst - 0.5f * (v0*v0 + v1*v1 + v2*v2 + v3*v3);
            mm_c1 = dppMaxAll(lq); e_c1 = __expf(lq - mm_c1);
        }

#pragma unroll 1
        for (int t = 1; t < T_LEN; ++t) {
            int o = ((t + 1 < T_LEN) ? (t + 1) : t) * 6;
            float y00 = X0[o], y01 = X0[o+1], y02 = X0[o+2], y03 = X0[o+3];
            float y10 = X1[o], y11 = X1[o+1], y12 = X1[o+2], y13 = X1[o+3];

            // both chains' readlane reduces interleaved (independent -> fill hazards)
            int ub0 = __float_as_int(u0);
            int ub1 = __float_as_int(u1);
            float qa0 = 0.f, qa1 = 0.f, qa2 = 0.f, qa3 = 0.f;
            float qb0 = 0.f, qb1 = 0.f, qb2 = 0.f, qb3 = 0.f;
#pragma unroll
            for (int k = 0; k < 16; ++k) {
                qa0 = fmaf(rlane(ub0, 4*k+0), Ac[4*k+0], qa0);
                qb0 = fmaf(rlane(ub1, 4*k+0), Ac[4*k+0], qb0);
                qa1 = fmaf(rlane(ub0, 4*k+1), Ac[4*k+1], qa1);
                qb1 = fmaf(rlane(ub1, 4*k+1), Ac[4*k+1], qb1);
                qa2 = fmaf(rlane(ub0, 4*k+2), Ac[4*k+2], qa2);
                qb2 = fmaf(rlane(ub1, 4*k+2), Ac[4*k+2], qb2);
                qa3 = fmaf(rlane(ub0, 4*k+3), Ac[4*k+3], qa3);
                qb3 = fmaf(rlane(ub1, 4*k+3), Ac[4*k+3], qb3);
            }
            u0 = ((qa0 + qa1) + (qa2 + qa3)) * e_c0;
            u1 = ((qb0 + qb1) + (qb2 + qb3)) * e_c1;
            acc0 += (double)mm_c0;
            acc1 += (double)mm_c1;
            if ((t & 3) == 0) {      // deferred renorm (round-9 proven)
                float s0 = dppSumAll(u0);
                float s1 = dppSumAll(u1);
                acc0 += (double)__logf(s0); u0 *= (1.0f / s0);
                acc1 += (double)__logf(s1); u1 *= (1.0f / s1);
            }

            // emissions t+1 (both)
            float w0 = (y00-mu0)*i0, w1 = (y01-mu1)*i1, w2 = (y02-mu2)*i2, w3 = (y03-mu3)*i3;
            float lp = cst - 0.5f * (w0*w0 + w1*w1 + w2*w2 + w3*w3);
            float v0 = (y10-mu0)*i0, v1 = (y11-mu1)*i1, v2 = (y12-mu2)*i2, v3 = (y13-mu3)*i3;
            float lq = cst - 0.5f * (v0*v0 + v1*v1 + v2*v2 + v3*v3);
            float mn0 = dppMaxAll(lp);
            float mn1 = dppMaxAll(lq);
            e_c0 = __expf(lp - mn0); mm_c0 = mn0;
            e_c1 = __expf(lq - mn1); mm_c1 = mn1;
        }
        float sf0 = dppSumAll(u0);
        float sf1 = dppSumAll(u1);
        acc0 += (double)__logf(sf0);
        acc1 += (double)__logf(sf1);
        if (j == 0) { out[b0] = (float)acc0; out[b1] = (float)acc1; }
    } else {
        // ---------------- VITERBI x2: exact lp from buf, in-place d-over-lp, readlane ----------------
        float lA[64];
        {
            const float4* g = (const float4*)lAg;
#pragma unroll
            for (int k = 0; k < 16; ++k) {
                float4 v = g[j * 16 + k];
                lA[4 * k + 0] = v.x; lA[4 * k + 1] = v.y;
                lA[4 * k + 2] = v.z; lA[4 * k + 3] = v.w;
            }
        }
        float* bb0 = buf + (size_t)b0 * T_LEN * 64 + j;
        float* bb1 = buf + (size_t)b1 * T_LEN * 64 + j;

        float dn0 = bb0[0] + lpi;
        float dn1 = bb1[0] + lpi;
        // 4-deep lp prefetch per chain
        float a0 = bb0[64], a1 = bb0[128], a2 = bb0[192], a3 = bb0[256];
        float c0 = bb1[64], c1 = bb1[128], c2 = bb1[192], c3 = bb1[256];
        bb0[0] = dn0; bb1[0] = dn1;

#pragma unroll 1
        for (int t = 1; t < T_LEN; ++t) {
            float lp0 = a0; a0 = a1; a1 = a2; a2 = a3;
            float lp1 = c0; c0 = c1; c1 = c2; c2 = c3;
            int tp = t + 4; if (tp > T_LEN - 1) tp = T_LEN - 1;
            a3 = bb0[(size_t)tp * 64];
            c3 = bb1[(size_t)tp * 64];

            int db0 = __float_as_int(dn0);
            int db1 = __float_as_int(dn1);
            float m00 = -3.4e38f, m01 = -3.4e38f, m02 = -3.4e38f, m03 = -3.4e38f;
            float m10 = -3.4e38f, m11 = -3.4e38f, m12 = -3.4e38f, m13 = -3.4e38f;
#pragma unroll
            for (int k = 0; k < 16; ++k) {
                float t00 = rlane(db0, 4*k+0) + lA[4*k+0];
                float t10 = rlane(db1, 4*k+0) + lA[4*k+0];
                float t01 = rlane(db0, 4*k+1) + lA[4*k+1];
                float t11 = rlane(db1, 4*k+1) + lA[4*k+1];
                float t02 = rlane(db0, 4*k+2) + lA[4*k+2];
                float t12 = rlane(db1, 4*k+2) + lA[4*k+2];
                float t03 = rlane(db0, 4*k+3) + lA[4*k+3];
                float t13 = rlane(db1, 4*k+3) + lA[4*k+3];
                m00 = fmaxf(m00, t00); m10 = fmaxf(m10, t10);   // max assoc: bit-exact
                m01 = fmaxf(m01, t01); m11 = fmaxf(m11, t11);
                m02 = fmaxf(m02, t02); m12 = fmaxf(m12, t12);
                m03 = fmaxf(m03, t03); m13 = fmaxf(m13, t13);
            }
            dn0 = fmaxf(fmaxf(m00, m01), fmaxf(m02, m03)) + lp0;
            dn1 = fmaxf(fmaxf(m10, m11), fmaxf(m12, m13)) + lp1;
            bb0[(size_t)t * 64] = dn0;
            bb1[(size_t)t * 64] = dn1;
        }

        float v0 = dn0; int i0x = j;
        waveArgmax(v0, i0x);
        float v1 = dn1; int i1x = j;
        waveArgmax(v1, i1x);
        if (j == 0) { c_last[b0] = i0x; c_last[b1] = i1x; }
    }
}

// ===== psi recompute: persistent lA in regs, grid-stride over (t,b) pairs =====
extern "C" __global__ __launch_bounds__(256)
void hmm_psi(const float* __restrict__ buf,
             const float* __restrict__ lAg,
             unsigned char* __restrict__ psi)
{
    __shared__ __align__(16) float sd[4][64];
    const int warp = threadIdx.x >> 6;
    const int j = threadIdx.x & 63;
    const int wid = blockIdx.x * 4 + warp;        // 0..8191

    float lA[64];
    {
        const float4* g = (const float4*)lAg;
#pragma unroll
        for (int k = 0; k < 16; ++k) {
            float4 v = g[j * 16 + k];
            lA[4 * k + 0] = v.x; lA[4 * k + 1] = v.y;
            lA[4 * k + 2] = v.z; lA[4 * k + 3] = v.w;
        }
    }
    const float4* dv = (const float4*)sd[warp];
    const int NP = 2049 * B_SZ;

    for (int p = wid; p < NP; p += 8192) {
        const int t = (p >> 7) + 1;
        const int b = p & 127;
        float dval = buf[((size_t)b * T_LEN + (t - 1)) * 64 + j];
        sd[warp][j] = dval;    // same-wave in-order: reads below see it

        // round-5-verbatim argmax tracker (np.argmax first-occurrence semantics)
        float bv0 = -3.4e38f, bv1 = -3.4e38f, bv2 = -3.4e38f, bv3 = -3.4e38f;
        int bi0 = 0, bi1 = 1, bi2 = 2, bi3 = 3;
#pragma unroll
        for (int k = 0; k < 16; ++k) {
            float4 dd = dv[k];
            float v0 = dd.x + lA[4 * k + 0];
            float v1 = dd.y + lA[4 * k + 1];
            float v2 = dd.z + lA[4 * k + 2];
            float v3 = dd.w + lA[4 * k + 3];
            if (v0 > bv0) { bv0 = v0; bi0 = 4 * k + 0; }
            if (v1 > bv1) { bv1 = v1; bi1 = 4 * k + 1; }
            if (v2 > bv2) { bv2 = v2; bi2 = 4 * k + 2; }
            if (v3 > bv3) { bv3 = v3; bi3 = 4 * k + 3; }
        }
        float best = bv0; int bidx = bi0;
        if (bv1 > best || (bv1 == best && bi1 < bidx)) { best = bv1; bidx = bi1; }
        if (bv2 > best || (bv2 == best && bi2 < bidx)) { best = bv2; bidx = bi2; }
        if (bv3 > best || (bv3 == best && bi3 < bidx)) { best = bv3; bidx = bi3; }

        psi[((size_t)t * B_SZ + b) * 64 + j] = (unsigned char)bidx;
    }
}

// ===== per-chunk backpointer composition: wave per (b, g) =====
extern "C" __global__ __launch_bounds__(256)
void hmm_compose(const unsigned char* __restrict__ psi,
                 unsigned char* __restrict__ mt)
{
    const int w = blockIdx.x * 4 + (threadIdx.x >> 6);   // 0 .. 4223
    const int j = threadIdx.x & 63;
    const int g = w % NCHUNK;
    const int b = w / NCHUNK;
    const int e = (g < NCHUNK - 1) ? g * 64 + 64 : (T_LEN - 1);
    int M = j;
    for (int t = e; t >= g * 64 + 1; --t)
        M = psi[((size_t)t * B_SZ + b) * 64 + M];
    mt[((size_t)g * B_SZ + b) * 64 + j] = (unsigned char)M;
}

// ===== boundary walk + parallel chunk fill: block per batch =====
extern "C" __global__ __launch_bounds__(64, 1)
void hmm_fill(const unsigned char* __restrict__ psi,
              const unsigned char* __restrict__ mt,
              const int* __restrict__ c_last,
              float* __restrict__ out)
{
    __shared__ int sb[NCHUNK];       // sb[g] = state at t = 64*g
    const int b = blockIdx.x;
    const int g = threadIdx.x;
    const int cl = c_last[b];
    if (g == 0) {
        int cur = cl;
        for (int q = NCHUNK - 1; q >= 0; --q) {
            cur = mt[((size_t)q * B_SZ + b) * 64 + cur];
            sb[q] = cur;
        }
    }
    cfence();   // single wave, in-order DS
    float* oc = out + B_SZ + (size_t)b * T_LEN;
    if (g == NCHUNK) {
        oc[T_LEN - 1] = (float)cl;
    } else if (g < NCHUNK) {
        const int e = (g < NCHUNK - 1) ? g * 64 + 64 : (T_LEN - 1);
        int s = (g < NCHUNK - 1) ? sb[g + 1] : cl;
        for (int t = e; t >= g * 64 + 1; --t) {
            s = psi[((size_t)t * B_SZ + b) * 64 + s];
            oc[t - 1] = (float)s;
        }
    }
}

extern "C" void kernel_launch(void* const* d_in, const int* in_sizes, int n_in,
                              void* d_out, int out_size, void* d_ws, size_t ws_size,
                              hipStream_t stream)
{
    const float* x      = (const float*)d_in[0];
    const float* means  = (const float*)d_in[1];
    const float* stds   = (const float*)d_in[2];
    const float* logA   = (const float*)d_in[3];
    const float* logpi  = (const float*)d_in[4];
    float* out = (float*)d_out;

    // workspace: 84,255,488 B total (proven to fit)
    char* base = (char*)d_ws;
    float*         buf  = (float*)base;                                  // 67,174,400 (lp then d, in place)
    unsigned char* psi  = (unsigned char*)(base + 67174400);             // 16,793,600
    unsigned char* mt   = (unsigned char*)(base + 83968000);             //    270,336
    int*           cl   = (int*)(base + 84238336);                       //        512
    float*         lAg  = (float*)(base + 84238848);                     //     16,384
    float*         lpig = (float*)(base + 84255232);                     //        256

    hipLaunchKernelGGL(hmm_prep, dim3(1), dim3(64), 0, stream, logA, logpi, lAg, lpig);
    hipLaunchKernelGGL(hmm_emis, dim3((T_LEN * B_SZ) / 4), dim3(256), 0, stream,
                       x, means, stds, buf);
    hipLaunchKernelGGL(hmm_main, dim3(B_SZ), dim3(64), 0, stream,
                       x, means, stds, lAg, lpig, out, buf, cl);
    hipLaunchKernelGGL(hmm_psi, dim3(2048), dim3(256), 0, stream, buf, lAg, psi);
    hipLaunchKernelGGL(hmm_compose, dim3((NCHUNK * B_SZ) / 4), dim3(256), 0, stream, psi, mt);
    hipLaunchKernelGGL(hmm_fill, dim3(B_SZ), dim3(64), 0, stream, psi, mt, cl, out);
}

// Round 11
// 1055.723 us; speedup vs baseline: 2.1368x; 2.1368x over previous
//
#include <hip/hip_runtime.h>

#define T_LEN 2050
#define B_SZ 128
#define NCHUNK 33               // chunks of steps t=1..2049
#define HL2PI 0.91893853320467274178f

// ---------- wave-wide helpers (wave = 64 lanes) ----------
__device__ __forceinline__ float waveMax(float v) {
#pragma unroll
    for (int off = 32; off >= 1; off >>= 1)
        v = fmaxf(v, __shfl_xor(v, off, 64));
    return v;
}
__device__ __forceinline__ float waveSum(float v) {
#pragma unroll
    for (int off = 32; off >= 1; off >>= 1)
        v += __shfl_xor(v, off, 64);
    return v;
}
__device__ __forceinline__ void waveArgmax(float& v, int& idx) {
#pragma unroll
    for (int off = 32; off >= 1; off >>= 1) {
        float ov = __shfl_xor(v, off, 64);
        int   oi = __shfl_xor(idx, off, 64);
        if (ov > v || (ov == v && oi < idx)) { v = ov; idx = oi; }
    }
}
__device__ __forceinline__ void cfence() { asm volatile("" ::: "memory"); }

// DPP full-wave reductions (rounds 5-10 proven)
__device__ __forceinline__ float dppSumAll(float v) {
#define SSTEP(ctrl) { int t_ = __builtin_amdgcn_update_dpp(0, __float_as_int(v), ctrl, 0xf, 0xf, true); \
                      v = v + __int_as_float(t_); }
    SSTEP(0x111) SSTEP(0x112) SSTEP(0x114) SSTEP(0x118) SSTEP(0x142) SSTEP(0x143)
#undef SSTEP
    return __int_as_float(__builtin_amdgcn_readlane(__float_as_int(v), 63));
}
__device__ __forceinline__ float dppMaxAll(float v) {
#define MSTEP(ctrl) { int t_ = __builtin_amdgcn_update_dpp(__float_as_int(v), __float_as_int(v), ctrl, 0xf, 0xf, false); \
                      v = fmaxf(v, __int_as_float(t_)); }
    MSTEP(0x111) MSTEP(0x112) MSTEP(0x114) MSTEP(0x118) MSTEP(0x142) MSTEP(0x143)
#undef MSTEP
    return __int_as_float(__builtin_amdgcn_readlane(__float_as_int(v), 63));
}

// ===== prep: log_softmax(log_A) -> lAg[c*64+i] (column-major), log_softmax(log_pi) =====
extern "C" __global__ __launch_bounds__(64, 1)
void hmm_prep(const float* __restrict__ logA_in,
              const float* __restrict__ logpi_in,
              float* __restrict__ lAg,
              float* __restrict__ lpig)
{
    __shared__ float la[64 * 65];
    __shared__ float rowlse[64];
    const int j = threadIdx.x;
#pragma unroll
    for (int k = 0; k < 64; ++k)
        la[k * 65 + j] = logA_in[k * 64 + j];
    cfence();
    {   // exact op order (rounds 1..10 proven)
        float m = -1e30f;
#pragma unroll
        for (int k = 0; k < 64; ++k) m = fmaxf(m, la[j * 65 + k]);
        float s = 0.f;
#pragma unroll
        for (int k = 0; k < 64; ++k) s += expf(la[j * 65 + k] - m);
        rowlse[j] = m + logf(s);
    }
    cfence();
    {
        float v = logpi_in[j];
        float m = waveMax(v);
        float s = waveSum(expf(v - m));
        lpig[j] = v - (m + logf(s));
    }
    float4* o = (float4*)lAg;
#pragma unroll
    for (int k = 0; k < 16; ++k) {
        float4 v;
        v.x = la[(4 * k + 0) * 65 + j] - rowlse[4 * k + 0];
        v.y = la[(4 * k + 1) * 65 + j] - rowlse[4 * k + 1];
        v.z = la[(4 * k + 2) * 65 + j] - rowlse[4 * k + 2];
        v.w = la[(4 * k + 3) * 65 + j] - rowlse[4 * k + 3];
        o[j * 16 + k] = v;
    }
}

// ===== emission precompute (EXACT op order, round-2 proven bit-exact) -> buf[b][t][64], m_pre[b][t] =====
extern "C" __global__ __launch_bounds__(256)
void hmm_emis(const float* __restrict__ x,
              const float* __restrict__ means,
              const float* __restrict__ stds,
              float* __restrict__ buf,
              float* __restrict__ m_pre)
{
    const int wid = blockIdx.x * 4 + (threadIdx.x >> 6);
    const int j = threadIdx.x & 63;
    const int t = wid >> 7;          // wid = t*128 + b
    const int b = wid & 127;

    const float* xt = x + ((size_t)b * T_LEN + t) * 6;
    float x0 = xt[0], x1 = xt[1], x2 = xt[2], x3 = xt[3];

    float mu0 = means[j * 6 + 0], mu1 = means[j * 6 + 1];
    float mu2 = means[j * 6 + 2], mu3 = means[j * 6 + 3];
    float sg0 = fmaxf(stds[j * 6 + 0], 0.f) + 0.1f;
    float sg1 = fmaxf(stds[j * 6 + 1], 0.f) + 0.1f;
    float sg2 = fmaxf(stds[j * 6 + 2], 0.f) + 0.1f;
    float sg3 = fmaxf(stds[j * 6 + 3], 0.f) + 0.1f;
    float ls0 = logf(sg0), ls1 = logf(sg1), ls2 = logf(sg2), ls3 = logf(sg3);

    float z0 = (x0 - mu0) / sg0, z1 = (x1 - mu1) / sg1;
    float z2 = (x2 - mu2) / sg2, z3 = (x3 - mu3) / sg3;
    float e0 = ((-0.5f * z0) * z0 - ls0) - HL2PI;
    float e1 = ((-0.5f * z1) * z1 - ls1) - HL2PI;
    float e2 = ((-0.5f * z2) * z2 - ls2) - HL2PI;
    float e3 = ((-0.5f * z3) * z3 - ls3) - HL2PI;
    float lp = ((e0 + e1) + e2) + e3;

    buf[((size_t)b * T_LEN + t) * 64 + j] = lp;
    float mm = waveMax(lp);
    if (j == 0) m_pre[(size_t)b * T_LEN + t] = mm;
}

// ===== main: single wave per chain, LDS broadcast + stripped chain.
// blocks 0..127: forward -> out[b]; blocks 128..255: viterbi -> d over lp in buf, c_last =====
extern "C" __global__ __launch_bounds__(64, 1)
void hmm_main(const float* __restrict__ x,
              const float* __restrict__ means,
              const float* __restrict__ stds,
              const float* __restrict__ lAg,
              const float* __restrict__ lpig,
              float* __restrict__ out,
              float* __restrict__ buf,
              const float* __restrict__ m_pre,
              int* __restrict__ c_last)
{
    __shared__ __align__(16) float xs[12304];     // x[b] (forward half only)
    __shared__ __align__(16) float pbuf[64];      // write-then-readback broadcast

    const int j   = threadIdx.x;
    const int bid = blockIdx.x;
    const bool is_fwd = (bid < B_SZ);
    const int b = is_fwd ? bid : bid - B_SZ;

    float lpi = lpig[j];
    const float4* pv = (const float4*)pbuf;

    if (is_fwd) {
        // stage x (inline mul-path emissions — rounds 5-9 proven)
        {
            const float4* xg4 = (const float4*)(x + (size_t)b * T_LEN * 6);
            float4* xs4 = (float4*)xs;
            for (int i = j; i < 3075; i += 64) xs4[i] = xg4[i];
        }
        float mu0 = means[j * 6 + 0], mu1 = means[j * 6 + 1];
        float mu2 = means[j * 6 + 2], mu3 = means[j * 6 + 3];
        float sg0 = fmaxf(stds[j * 6 + 0], 0.f) + 0.1f;
        float sg1 = fmaxf(stds[j * 6 + 1], 0.f) + 0.1f;
        float sg2 = fmaxf(stds[j * 6 + 2], 0.f) + 0.1f;
        float sg3 = fmaxf(stds[j * 6 + 3], 0.f) + 0.1f;
        float ls0 = logf(sg0), ls1 = logf(sg1), ls2 = logf(sg2), ls3 = logf(sg3);
        float i0 = 1.f / sg0, i1 = 1.f / sg1, i2 = 1.f / sg2, i3 = 1.f / sg3;
        float cst = -(ls0 + ls1 + ls2 + ls3) - 4.f * HL2PI;

        float Ac[64];
        {
            const float4* g = (const float4*)lAg;
#pragma unroll
            for (int k = 0; k < 16; ++k) {
                float4 v = g[j * 16 + k];
                Ac[4 * k + 0] = __expf(v.x); Ac[4 * k + 1] = __expf(v.y);
                Ac[4 * k + 2] = __expf(v.z); Ac[4 * k + 3] = __expf(v.w);
            }
        }
        cfence();   // xs staged (same-wave in-order DS)

        // t = 0
        float z0 = (xs[0] - mu0) * i0, z1 = (xs[1] - mu1) * i1;
        float z2 = (xs[2] - mu2) * i2, z3 = (xs[3] - mu3) * i3;
        float a0 = (cst - 0.5f * (z0 * z0 + z1 * z1 + z2 * z2 + z3 * z3)) + lpi;
        float m0a = dppMaxAll(a0);
        float u = __expf(a0 - m0a);
        float s0 = dppSumAll(u);
        double acc = (double)(m0a + __logf(s0));
        u *= (1.0f / s0);
        pbuf[j] = u;
        float4 rr[16];
#pragma unroll
        for (int k = 0; k < 16; ++k) rr[k] = pv[k];

        // m_pre ring (4-deep prefetch), wave-uniform broadcast loads
        const float* mp = m_pre + (size_t)b * T_LEN;
        float g0 = mp[1], g1 = mp[2], g2 = mp[3], g3 = mp[4];

#pragma unroll 1
        for (int t = 1; t < T_LEN; ++t) {
            float mm_c = g0; g0 = g1; g1 = g2; g2 = g3;
            int tp = t + 4; if (tp > T_LEN - 1) tp = T_LEN - 1;
            g3 = mp[tp];

            // emission t (mul path; xs reads issued early)
            int o = t * 6;
            float y0 = xs[o], y1 = xs[o + 1], y2 = xs[o + 2], y3 = xs[o + 3];
            float w0 = (y0 - mu0) * i0, w1 = (y1 - mu1) * i1;
            float w2 = (y2 - mu2) * i2, w3 = (y3 - mu3) * i3;
            float lp = cst - 0.5f * (w0 * w0 + w1 * w1 + w2 * w2 + w3 * w3);
            float e_c = __expf(lp - mm_c);

            // reduce q = sum_i u[i]*A[i][j] from LDS-broadcast registers
            float q0 = 0.f, q1 = 0.f, q2 = 0.f, q3 = 0.f;
#pragma unroll
            for (int k = 0; k < 16; ++k) {
                float4 pp = rr[k];
                q0 = fmaf(pp.x, Ac[4 * k + 0], q0);
                q1 = fmaf(pp.y, Ac[4 * k + 1], q1);
                q2 = fmaf(pp.z, Ac[4 * k + 2], q2);
                q3 = fmaf(pp.w, Ac[4 * k + 3], q3);
            }
            u = ((q0 + q1) + (q2 + q3)) * e_c;
            acc += (double)mm_c;
            if ((t & 3) == 0) {          // deferred renorm (rounds 9/10 proven)
                float ss = dppSumAll(u);
                acc += (double)__logf(ss);
                u *= (1.0f / ss);
            }

            // publish + readback (same-wave in-order LDS)
            pbuf[j] = u;
#pragma unroll
            for (int k = 0; k < 16; ++k) rr[k] = pv[k];
        }
        float sf = dppSumAll(u);
        acc += (double)__logf(sf);
        if (j == 0) out[b] = (float)acc;
    } else {
        // ---------------- VITERBI: exact lp from buf (4-deep prefetch), LDS broadcast, in-place d ----------------
        float lA[64];
        {
            const float4* g = (const float4*)lAg;
#pragma unroll
            for (int k = 0; k < 16; ++k) {
                float4 v = g[j * 16 + k];
                lA[4 * k + 0] = v.x; lA[4 * k + 1] = v.y;
                lA[4 * k + 2] = v.z; lA[4 * k + 3] = v.w;
            }
        }
        float* bb = buf + (size_t)b * T_LEN * 64 + j;

        // t = 0
        float dn = bb[0] + lpi;
        float l0 = bb[64], l1 = bb[128], l2 = bb[192], l3 = bb[256];
        bb[0] = dn;
        pbuf[j] = dn;
        float4 rr[16];
#pragma unroll
        for (int k = 0; k < 16; ++k) rr[k] = pv[k];

#pragma unroll 1
        for (int t = 1; t < T_LEN; ++t) {
            float lp_c = l0; l0 = l1; l1 = l2; l2 = l3;
            int tp = t + 4; if (tp > T_LEN - 1) tp = T_LEN - 1;
            l3 = bb[(size_t)tp * 64];        // read t+4 before row t+4 is written

            // reduce best = max_i(d[i]+lA[i][j]) (4 independent chains; max assoc: bit-exact)
            float m0 = -3.4e38f, m1 = -3.4e38f, m2 = -3.4e38f, m3 = -3.4e38f;
#pragma unroll
            for (int k = 0; k < 16; ++k) {
                float4 dd = rr[k];
                m0 = fmaxf(m0, dd.x + lA[4 * k + 0]);
                m1 = fmaxf(m1, dd.y + lA[4 * k + 1]);
                m2 = fmaxf(m2, dd.z + lA[4 * k + 2]);
                m3 = fmaxf(m3, dd.w + lA[4 * k + 3]);
            }
            dn = fmaxf(fmaxf(m0, m1), fmaxf(m2, m3)) + lp_c;

            bb[(size_t)t * 64] = dn;         // overwrite lp row t with d row t
            pbuf[j] = dn;
#pragma unroll
            for (int k = 0; k < 16; ++k) rr[k] = pv[k];
        }

        float vv = dn; int idx = j;
        waveArgmax(vv, idx);
        if (j == 0) c_last[b] = idx;
    }
}

// ===== psi recompute: persistent lA in regs, grid-stride over (t,b) pairs =====
extern "C" __global__ __launch_bounds__(256)
void hmm_psi(const float* __restrict__ buf,
             const float* __restrict__ lAg,
             unsigned char* __restrict__ psi)
{
    __shared__ __align__(16) float sd[4][64];
    const int warp = threadIdx.x >> 6;
    const int j = threadIdx.x & 63;
    const int wid = blockIdx.x * 4 + warp;        // 0..8191

    float lA[64];
    {
        const float4* g = (const float4*)lAg;
#pragma unroll
        for (int k = 0; k < 16; ++k) {
            float4 v = g[j * 16 + k];
            lA[4 * k + 0] = v.x; lA[4 * k + 1] = v.y;
            lA[4 * k + 2] = v.z; lA[4 * k + 3] = v.w;
        }
    }
    const float4* dv = (const float4*)sd[warp];
    const int NP = 2049 * B_SZ;

    for (int p = wid; p < NP; p += 8192) {
        const int t = (p >> 7) + 1;
        const int b = p & 127;
        float dval = buf[((size_t)b * T_LEN + (t - 1)) * 64 + j];
        sd[warp][j] = dval;    // same-wave in-order: reads below see it

        // round-5-verbatim argmax tracker (np.argmax first-occurrence semantics)
        float bv0 = -3.4e38f, bv1 = -3.4e38f, bv2 = -3.4e38f, bv3 = -3.4e38f;
        int bi0 = 0, bi1 = 1, bi2 = 2, bi3 = 3;
#pragma unroll
        for (int k = 0; k < 16; ++k) {
            float4 dd = dv[k];
            float v0 = dd.x + lA[4 * k + 0];
            float v1 = dd.y + lA[4 * k + 1];
            float v2 = dd.z + lA[4 * k + 2];
            float v3 = dd.w + lA[4 * k + 3];
            if (v0 > bv0) { bv0 = v0; bi0 = 4 * k + 0; }
            if (v1 > bv1) { bv1 = v1; bi1 = 4 * k + 1; }
            if (v2 > bv2) { bv2 = v2; bi2 = 4 * k + 2; }
            if (v3 > bv3) { bv3 = v3; bi3 = 4 * k + 3; }
        }
        float best = bv0; int bidx = bi0;
        if (bv1 > best || (bv1 == best && bi1 < bidx)) { best = bv1; bidx = bi1; }
        if (bv2 > best || (bv2 == best && bi2 < bidx)) { best = bv2; bidx = bi2; }
        if (bv3 > best || (bv3 == best && bi3 < bidx)) { best = bv3; bidx = bi3; }

        psi[((size_t)t * B_SZ + b) * 64 + j] = (unsigned char)bidx;
    }
}

// ===== per-chunk backpointer composition: wave per (b, g) =====
extern "C" __global__ __launch_bounds__(256)
void hmm_compose(const unsigned char* __restrict__ psi,
                 unsigned char* __restrict__ mt)
{
    const int w = blockIdx.x * 4 + (threadIdx.x >> 6);   // 0 .. 4223
    const int j = threadIdx.x & 63;
    const int g = w % NCHUNK;
    const int b = w / NCHUNK;
    const int e = (g < NCHUNK - 1) ? g * 64 + 64 : (T_LEN - 1);
    int M = j;
    for (int t = e; t >= g * 64 + 1; --t)
        M = psi[((size_t)t * B_SZ + b) * 64 + M];
    mt[((size_t)g * B_SZ + b) * 64 + j] = (unsigned char)M;
}

// ===== boundary walk + parallel chunk fill: block per batch =====
extern "C" __global__ __launch_bounds__(64, 1)
void hmm_fill(const unsigned char* __restrict__ psi,
              const unsigned char* __restrict__ mt,
              const int* __restrict__ c_last,
              float* __restrict__ out)
{
    __shared__ int sb[NCHUNK];       // sb[g] = state at t = 64*g
    const int b = blockIdx.x;
    const int g = threadIdx.x;
    const int cl = c_last[b];
    if (g == 0) {
        int cur = cl;
        for (int q = NCHUNK - 1; q >= 0; --q) {
            cur = mt[((size_t)q * B_SZ + b) * 64 + cur];
            sb[q] = cur;
        }
    }
    cfence();   // single wave, in-order DS
    float* oc = out + B_SZ + (size_t)b * T_LEN;
    if (g == NCHUNK) {
        oc[T_LEN - 1] = (float)cl;
    } else if (g < NCHUNK) {
        const int e = (g < NCHUNK - 1) ? g * 64 + 64 : (T_LEN - 1);
        int s = (g < NCHUNK - 1) ? sb[g + 1] : cl;
        for (int t = e; t >= g * 64 + 1; --t) {
            s = psi[((size_t)t * B_SZ + b) * 64 + s];
            oc[t - 1] = (float)s;
        }
    }
}

extern "C" void kernel_launch(void* const* d_in, const int* in_sizes, int n_in,
                              void* d_out, int out_size, void* d_ws, size_t ws_size,
                              hipStream_t stream)
{
    const float* x      = (const float*)d_in[0];
    const float* means  = (const float*)d_in[1];
    const float* stds   = (const float*)d_in[2];
    const float* logA   = (const float*)d_in[3];
    const float* logpi  = (const float*)d_in[4];
    float* out = (float*)d_out;

    // workspace: 84,255,488 B (proven to fit). m_pre overlaps the psi region:
    // m_pre (1 MB) is consumed by hmm_main and only then does hmm_psi overwrite psi.
    char* base = (char*)d_ws;
    float*         buf   = (float*)base;                                 // 67,174,400 (lp then d, in place)
    unsigned char* psi   = (unsigned char*)(base + 67174400);            // 16,793,600
    float*         m_pre = (float*)(base + 67174400);                    //  1,049,600 (dead after hmm_main)
    unsigned char* mt    = (unsigned char*)(base + 83968000);            //    270,336
    int*           cl    = (int*)(base + 84238336);                      //        512
    float*         lAg   = (float*)(base + 84238848);                    //     16,384
    float*         lpig  = (float*)(base + 84255232);                    //        256

    hipLaunchKernelGGL(hmm_prep, dim3(1), dim3(64), 0, stream, logA, logpi, lAg, lpig);
    hipLaunchKernelGGL(hmm_emis, dim3((T_LEN * B_SZ) / 4), dim3(256), 0, stream,
                       x, means, stds, buf, m_pre);
    hipLaunchKernelGGL(hmm_main, dim3(2 * B_SZ), dim3(64), 0, stream,
                       x, means, stds, lAg, lpig, out, buf, m_pre, cl);
    hipLaunchKernelGGL(hmm_psi, dim3(2048), dim3(256), 0, stream, buf, lAg, psi);
    hipLaunchKernelGGL(hmm_compose, dim3((NCHUNK * B_SZ) / 4), dim3(256), 0, stream, psi, mt);
    hipLaunchKernelGGL(hmm_fill, dim3(B_SZ), dim3(64), 0, stream, psi, mt, cl, out);
}